// Round 2
// baseline (334.481 us; speedup 1.0000x reference)
//
#include <hip/hip_runtime.h>
#include <hip/hip_bf16.h>

// ConceptBottleneck fused kernel, MI355X (gfx950).
// B=8192, IN=768, C=64, H=64, E=16.  Inputs/outputs fp32; internal math bf16 MFMA.
// prep_all: ONE flat-grid launch — LDS-tiled transposes of [K x 64] weights plus
//           grid-strided fp32->bf16 copies / small strided transposes.
// cb_fused_t: grid (B/128, C); block = 128-row batch tile x one concept.
//   R2 (this): ASYNC double-buffered L1 via global_load_lds + counted vmcnt.
//   L1 tiles are [256 rows][64 cols] bf16 stride-64 (x rows 0-127, pos W1 128-191,
//   neg W1 192-255), XOR-swizzled: global source chunk (l&7)^(l>>3) written
//   linearly; reads XOR chunk with (row&7). 2-way bank alias only (free, m136).
//   Per K-step: issue 8 gll dwordx4 for tile k+1 into buf^1 -> s_waitcnt vmcnt(8)
//   (NEVER 0 in loop) -> raw s_barrier -> 32 MFMAs -> raw s_barrier. In-flight
//   tile lives in the vmcnt counter, NOT VGPRs -> side-steps the SPILL LAW
//   (prev session R4/R5/R7: register state across __syncthreads gets spilled).
//   LDS 76288 B -> 2 blocks/CU. Tail phases reuse bufA/bufB as stride-72 hb/wt.

#define B_   8192
#define IN_  768
#define C_   64
#define H_   64
#define E_   16
#define BM_  128

typedef __bf16 bf16x8 __attribute__((ext_vector_type(8)));
typedef float  f32x4  __attribute__((ext_vector_type(4)));

__device__ __forceinline__ f32x4 mfma16(bf16x8 a, bf16x8 b, f32x4 c) {
  return __builtin_amdgcn_mfma_f32_16x16x32_bf16(a, b, c, 0, 0, 0);
}

__device__ __forceinline__ bf16x8 cvt8(float4 a, float4 b) {
  bf16x8 r;
  r[0] = (__bf16)a.x; r[1] = (__bf16)a.y; r[2] = (__bf16)a.z; r[3] = (__bf16)a.w;
  r[4] = (__bf16)b.x; r[5] = (__bf16)b.y; r[6] = (__bf16)b.z; r[7] = (__bf16)b.w;
  return r;
}

__device__ __forceinline__ void zero_acc(f32x4 (&acc)[2][4]) {
  const f32x4 z = {0.f, 0.f, 0.f, 0.f};
#pragma unroll
  for (int mt = 0; mt < 2; ++mt)
#pragma unroll
    for (int nt = 0; nt < 4; ++nt) acc[mt][nt] = z;
}

// 16B global -> LDS direct (vmcnt-counted; LDS dest = wave-uniform base + lane*16)
__device__ __forceinline__ void gll16(const __bf16* g, __bf16* l) {
  __builtin_amdgcn_global_load_lds(
      (const __attribute__((address_space(1))) unsigned int*)g,
      (__attribute__((address_space(3))) unsigned int*)l, 16, 0, 0);
}

#define FENCE asm volatile("" ::: "memory")

// ============================ MAIN KERNEL ===================================
// LDS (76288 B -> 2 blocks/CU):
//  bufA[256*64] : L1 tile buffer 0 | tail: hb [128][72] activations
//  bufB[256*64] : L1 tile buffer 1 | tail: wt [128][72] weights
//  xcb[128][40] : pos|neg embeddings (cols 0..15 pos, 16..31 neg)
struct __align__(16) SmemT {
  __bf16 bufA[256 * 64];
  __bf16 bufB[256 * 64];
  __bf16 xcb[BM_ * 40];
  float  conc[BM_];
};
static_assert(sizeof(SmemT) == 76288, "layout");
static_assert(sizeof(SmemT) <= 81920, "LDS: need 2 blocks/CU");

// Epilogue: C/D frags (col=lane&15, row=quad*4+reg) + fp32 bias, relu -> hb (stride 72)
__device__ __forceinline__ void epi72(__bf16* __restrict__ hb, f32x4 (&acc)[2][4],
                                      const float* __restrict__ bias,
                                      int wave, int quad, int l16) {
#pragma unroll
  for (int nt = 0; nt < 4; ++nt) {
    const int col = nt * 16 + l16;
    const float bv = bias[col];
#pragma unroll
    for (int mt = 0; mt < 2; ++mt)
#pragma unroll
      for (int r = 0; r < 4; ++r) {
        int row = wave * 32 + mt * 16 + quad * 4 + r;
        hb[row * 72 + col] = (__bf16)fmaxf(acc[mt][nt][r] + bv, 0.f);
      }
  }
}

// [128,64] @ [64,64]: A=hb (stride 72), B=wt [n][k] (stride 72), K=64.
__device__ __forceinline__ void gemm64(const __bf16* __restrict__ hb,
                                       const __bf16* __restrict__ wt,
                                       f32x4 (&acc)[2][4], int wave, int quad, int l16) {
#pragma unroll
  for (int ks = 0; ks < 2; ++ks) {
    bf16x8 a[2], bb[4];
#pragma unroll
    for (int mt = 0; mt < 2; ++mt)
      a[mt] = *(const bf16x8*)(hb + (wave * 32 + mt * 16 + l16) * 72 + ks * 32 + quad * 8);
#pragma unroll
    for (int nt = 0; nt < 4; ++nt)
      bb[nt] = *(const bf16x8*)(wt + (nt * 16 + l16) * 72 + ks * 32 + quad * 8);
#pragma unroll
    for (int mt = 0; mt < 2; ++mt)
#pragma unroll
      for (int nt = 0; nt < 4; ++nt)
        acc[mt][nt] = mfma16(a[mt], bb[nt], acc[mt][nt]);
  }
}

// Stage [64][64] bf16 tile (row-major contiguous) into wt (stride 72). 2 b128/thread.
__device__ __forceinline__ void stage_w64(const __bf16* __restrict__ Wt,
                                          __bf16* __restrict__ wt, int tid) {
#pragma unroll
  for (int it = 0; it < 2; ++it) {
    int q = tid + it * 256;
    int n = q >> 3, i = q & 7;
    *(uint4*)&wt[n * 72 + i * 8] = *(const uint4*)(Wt + n * 64 + i * 8);
  }
}

// Layer-3 tile: e = h2 @ W3^T -> xcb[:, xc_off..+16).  wt16 = [16][64] at stride 72.
__device__ __forceinline__ void l3_tile(const __bf16* __restrict__ hb,
                                        const __bf16* __restrict__ wt16,
                                        __bf16* __restrict__ xcb,
                                        const float* __restrict__ b3, int xc_off,
                                        int wave, int quad, int l16) {
  f32x4 acc3[2];
  { const f32x4 z = {0.f, 0.f, 0.f, 0.f}; acc3[0] = z; acc3[1] = z; }
#pragma unroll
  for (int ks = 0; ks < 2; ++ks) {
    bf16x8 bb = *(const bf16x8*)(wt16 + l16 * 72 + ks * 32 + quad * 8);
#pragma unroll
    for (int mt = 0; mt < 2; ++mt) {
      bf16x8 a = *(const bf16x8*)(hb + (wave * 32 + mt * 16 + l16) * 72 + ks * 32 + quad * 8);
      acc3[mt] = mfma16(a, bb, acc3[mt]);
    }
  }
  const float bv = b3[l16];
#pragma unroll
  for (int mt = 0; mt < 2; ++mt)
#pragma unroll
    for (int r = 0; r < 4; ++r) {
      int row = wave * 32 + mt * 16 + quad * 4 + r;
      xcb[row * 40 + xc_off + l16] = (__bf16)(acc3[mt][r] + bv);
    }
}

// L1 MFMA step on a [256][64] swizzled buffer: rows 0-127 x, 128-191 posW, 192-255 negW.
__device__ __forceinline__ void l1_step(const __bf16* __restrict__ cbuf,
                                        f32x4 (&accP)[2][4], f32x4 (&accN)[2][4],
                                        int wave, int quad, int l16) {
  const int sx = l16 & 7;   // row&7 for all fragment rows
#pragma unroll
  for (int ks = 0; ks < 2; ++ks) {
    const int pc = (((ks * 4 + quad) ^ sx)) * 8;   // swizzled chunk -> element offset
    bf16x8 a[2], bp[4], bn[4];
#pragma unroll
    for (int mt = 0; mt < 2; ++mt)
      a[mt] = *(const bf16x8*)(cbuf + (wave * 32 + mt * 16 + l16) * 64 + pc);
#pragma unroll
    for (int nt = 0; nt < 4; ++nt) {
      bp[nt] = *(const bf16x8*)(cbuf + (128 + nt * 16 + l16) * 64 + pc);
      bn[nt] = *(const bf16x8*)(cbuf + (192 + nt * 16 + l16) * 64 + pc);
    }
#pragma unroll
    for (int mt = 0; mt < 2; ++mt)
#pragma unroll
      for (int nt = 0; nt < 4; ++nt) {
        accP[mt][nt] = mfma16(a[mt], bp[nt], accP[mt][nt]);
        accN[mt][nt] = mfma16(a[mt], bn[nt], accN[mt][nt]);
      }
  }
}

__global__ __launch_bounds__(256, 2) void cb_fused_t(
    const __bf16* __restrict__ x,
    const __bf16* __restrict__ pW1t, const float* __restrict__ pb1,
    const __bf16* __restrict__ pW2t, const float* __restrict__ pb2,
    const __bf16* __restrict__ pW3t, const float* __restrict__ pb3,
    const __bf16* __restrict__ nW1t, const float* __restrict__ nb1,
    const __bf16* __restrict__ nW2t, const float* __restrict__ nb2,
    const __bf16* __restrict__ nW3t, const float* __restrict__ nb3,
    const __bf16* __restrict__ cW1t, const float* __restrict__ cb1,
    const __bf16* __restrict__ cW2t, const float* __restrict__ cb2,
    const __bf16* __restrict__ cw3,  const float* __restrict__ cb3,
    float* __restrict__ out_emb, float* __restrict__ out_con)
{
  __shared__ SmemT sm;
  const int tid  = threadIdx.x;
  const int wave = tid >> 6, lane = tid & 63;
  const int quad = lane >> 4, l16 = lane & 15;
  const int row0 = blockIdx.x * BM_;
  const int c    = blockIdx.y;
  __bf16* hb = sm.bufA;   // tail alias (stride 72)
  __bf16* wt = sm.bufB;   // tail alias (stride 72)

  // per-concept pointers
  const __bf16* pg   = pW1t + (size_t)c * 64 * IN_;
  const __bf16* ng   = nW1t + (size_t)c * 64 * IN_;
  const float*  pb1c = pb1 + c * 64;
  const float*  nb1c = nb1 + c * 64;
  const float*  pb2c = pb2 + c * 64;
  const float*  nb2c = nb2 + c * 64;

  // ---------- layer 1 COMBINED, async double-buffered ----------
  // Wave roles (64 rows each, 8 segments of 8 rows): w0/w1 -> x rows 0-127,
  // w2 -> pos W1, w3 -> neg W1. Lane l loads global chunk (l&7)^(l>>3) of row
  // seg*8+(l>>3); HW writes linearly -> LDS holds chunk c of row r at c^(r&7).
  f32x4 accP[2][4]; zero_acc(accP);
  f32x4 accN[2][4]; zero_acc(accN);

  const __bf16* xg = x + (size_t)row0 * IN_;
  const int lrow   = lane >> 3;             // 0..7 within segment
  const int lchunk = (lane & 7) ^ lrow;     // swizzled source chunk
  const __bf16* gsrc = (wave == 0) ? xg
                     : (wave == 1) ? xg + 64 * IN_
                     : (wave == 2) ? pg : ng;
  const __bf16* gl = gsrc + (size_t)lrow * IN_ + lchunk * 8;  // per-lane base
  __bf16* const dA = sm.bufA + wave * 64 * 64;   // wave-uniform LDS bases
  __bf16* const dB = sm.bufB + wave * 64 * 64;

  // prologue: tile 0 -> bufA
#pragma unroll
  for (int j = 0; j < 8; ++j)
    gll16(gl + j * 8 * IN_, dA + j * 8 * 64);

  for (int kt = 0; kt < 11; ++kt) {
    // issue tile kt+1 into the other buffer (stays in flight across barriers)
    {
      const __bf16* gk = gl + (kt + 1) * 64;
      __bf16* nd = (kt & 1) ? dA : dB;
#pragma unroll
      for (int j = 0; j < 8; ++j)
        gll16(gk + j * 8 * IN_, nd + j * 8 * 64);
    }
    // wait tile kt (8 older ops) landed; tile kt+1 (8 newest) still in flight
    asm volatile("s_waitcnt vmcnt(8)" ::: "memory");
    __builtin_amdgcn_s_barrier();
    __builtin_amdgcn_sched_barrier(0);
    FENCE;
    l1_step((kt & 1) ? sm.bufB : sm.bufA, accP, accN, wave, quad, l16);
    FENCE;
    __builtin_amdgcn_s_barrier();   // reads done before next iter overwrites
    __builtin_amdgcn_sched_barrier(0);
    FENCE;
  }
  // peeled last tile (kt=11, data in bufB): full drain is fine here
  __syncthreads();                  // emits s_waitcnt vmcnt(0) lgkmcnt(0) + barrier
  l1_step(sm.bufB, accP, accN, wave, quad, l16);
  __syncthreads();

  // ---------- layer 1 epilogue (pos) + stage both W2 tiles ----------
  epi72(hb, accP, pb1c, wave, quad, l16);                   // h1_pos -> hb (bufA)
  stage_w64(pW2t + (size_t)c * 64 * 64, wt, tid);           // wt rows 0-63
  stage_w64(nW2t + (size_t)c * 64 * 64, wt + 64 * 72, tid); // wt rows 64-127
  __syncthreads();

  // ---------- layer 2 pos: [128,64] @ [64,64] ----------
  f32x4 acc2P[2][4]; zero_acc(acc2P);
  gemm64(hb, wt, acc2P, wave, quad, l16);
  __syncthreads();

  // ---------- layer 1 epilogue (neg) + stage both W3 tiles (wt rows 0-31) ----
  epi72(hb, accN, nb1c, wave, quad, l16);                   // h1_neg -> hb
  {
    int n = tid >> 3, i = tid & 7;                          // 32 rows x 8 chunks
    const __bf16* src = (n < 16)
        ? (pW3t + (size_t)c * 16 * 64 + n * 64 + i * 8)
        : (nW3t + (size_t)c * 16 * 64 + (n - 16) * 64 + i * 8);
    *(uint4*)&wt[n * 72 + i * 8] = *(const uint4*)src;
  }
  __syncthreads();

  // ---------- layer 2 neg ----------
  f32x4 acc2N[2][4]; zero_acc(acc2N);
  gemm64(hb, wt + 64 * 72, acc2N, wave, quad, l16);
  __syncthreads();

  // ---------- layer 3 pos ----------
  epi72(hb, acc2P, pb2c, wave, quad, l16);                  // h2_pos -> hb
  __syncthreads();
  l3_tile(hb, wt, sm.xcb, pb3 + c * 16, 0, wave, quad, l16);
  __syncthreads();

  // ---------- layer 3 neg ----------
  epi72(hb, acc2N, nb2c, wave, quad, l16);                  // h2_neg -> hb
  __syncthreads();
  l3_tile(hb, wt + 16 * 72, sm.xcb, nb3 + c * 16, 16, wave, quad, l16);
  __syncthreads();

  // ---- cp layer 1: [128,32] @ [32,64]; A = xcb (stride 40), B = cW1t [64][32] ----
  {
    int n = tid >> 2, i = tid & 3;
    *(uint4*)&wt[n * 72 + i * 8] = *(const uint4*)(cW1t + ((size_t)c * 64 + n) * 32 + i * 8);
  }
  __syncthreads();
  f32x4 acc1[2][4]; zero_acc(acc1);
  {
    bf16x8 a[2], bb[4];
#pragma unroll
    for (int mt = 0; mt < 2; ++mt)
      a[mt] = *(const bf16x8*)&sm.xcb[(wave * 32 + mt * 16 + l16) * 40 + quad * 8];
#pragma unroll
    for (int nt = 0; nt < 4; ++nt)
      bb[nt] = *(const bf16x8*)&wt[(nt * 16 + l16) * 72 + quad * 8];
#pragma unroll
    for (int mt = 0; mt < 2; ++mt)
#pragma unroll
      for (int nt = 0; nt < 4; ++nt)
        acc1[mt][nt] = mfma16(a[mt], bb[nt], acc1[mt][nt]);
  }
  __syncthreads();
  epi72(hb, acc1, cb1 + c * 64, wave, quad, l16);
  stage_w64(cW2t + (size_t)c * 64 * 64, wt, tid);
  __syncthreads();

  // ---- cp layer 2 ----
  f32x4 acc2[2][4]; zero_acc(acc2);
  gemm64(hb, wt, acc2, wave, quad, l16);
  __syncthreads();
  epi72(hb, acc2, cb2 + c * 64, wave, quad, l16);
  if (tid < 8) *(uint4*)&wt[tid * 8] = *(const uint4*)(cw3 + (size_t)c * 64 + tid * 8);
  __syncthreads();

  // ---- cp layer 3 (N=1 via MFMA; B nonzero only in lane col 0) ----
  f32x4 acc3[2];
  { const f32x4 z = {0.f, 0.f, 0.f, 0.f}; acc3[0] = z; acc3[1] = z; }
#pragma unroll
  for (int ks = 0; ks < 2; ++ks) {
    bf16x8 bb = {};
    if (l16 == 0) bb = *(const bf16x8*)&wt[ks * 32 + quad * 8];
#pragma unroll
    for (int mt = 0; mt < 2; ++mt) {
      bf16x8 a = *(const bf16x8*)&hb[(wave * 32 + mt * 16 + l16) * 72 + ks * 32 + quad * 8];
      acc3[mt] = mfma16(a, bb, acc3[mt]);
    }
  }
  if (l16 == 0) {
    float bv = cb3[c];
#pragma unroll
    for (int mt = 0; mt < 2; ++mt)
#pragma unroll
      for (int r = 0; r < 4; ++r)
        sm.conc[wave * 32 + mt * 16 + quad * 4 + r] = acc3[mt][r] + bv;
  }
  __syncthreads();

  // ---- gate + outputs (fp32) ----
  for (int ii = tid; ii < BM_ * E_; ii += 256) {
    int row = ii >> 4, e = ii & 15;
    float cv = sm.conc[row];
    float w  = fminf(fmaxf(cv * 0.5f + 0.5f, 0.f), 1.f);
    float pv2 = (float)sm.xcb[row * 40 + e];
    float nv2 = (float)sm.xcb[row * 40 + 16 + e];
    out_emb[(size_t)(row0 + row) * (E_ * C_) + e * C_ + c] = pv2 * w + nv2 * (1.f - w);
  }
  if (tid < 128) out_con[(size_t)(row0 + tid) * C_ + c] = sm.conc[tid];
}

// ------------- prep_all: ONE flat 1D launch, no dead blocks -------------------
// Blocks [0, tblocks): LDS-tiled transpose of [C][K][64] fp32 -> [C][64][K] bf16.
// Blocks [tblocks, ..): grid-strided (4 chunks/thread) fp32->bf16 copies and
//   small strided transposes.
#define TSEG 5
#define PSEG 5
struct PrepArgs {
  const float* tsrc[TSEG];
  __bf16*      tdst[TSEG];
  int tstart[TSEG + 1];
  int ktiles[TSEG];            // K/64
  const float* psrc[PSEG];
  __bf16*      pdst[PSEG];
  int pstart[PSEG + 1];        // block starts (after tblocks)
  int pchunks[PSEG];           // total 8-elem chunks in segment
  int kdiv8[PSEG];
  int N[PSEG];                 // 1 = plain copy, else transpose inner stride
  int tblocks;
};

__global__ __launch_bounds__(256) void prep_all(PrepArgs a) {
  const int tid = threadIdx.x;
  const int b = blockIdx.x;
  __shared__ __bf16 lt[64 * 72];
  if (b < a.tblocks) {
    int s = 0;
    while (s < TSEG - 1 && b >= a.tstart[s + 1]) ++s;
    const int idx = b - a.tstart[s];
    const int kt = idx % a.ktiles[s];
    const int c  = idx / a.ktiles[s];
    const int K  = a.ktiles[s] * 64;
    const float* src = a.tsrc[s] + (size_t)c * K * 64 + (size_t)kt * 64 * 64;
    __bf16*      dst = a.tdst[s] + (size_t)c * 64 * K + kt * 64;
    const int r = tid >> 4, c4 = (tid & 15) * 4;
#pragma unroll
    for (int it = 0; it < 4; ++it) {
      int k = r + it * 16;
      float4 v = *(const float4*)(src + (size_t)k * 64 + c4);
      lt[(c4 + 0) * 72 + k] = (__bf16)v.x;
      lt[(c4 + 1) * 72 + k] = (__bf16)v.y;
      lt[(c4 + 2) * 72 + k] = (__bf16)v.z;
      lt[(c4 + 3) * 72 + k] = (__bf16)v.w;
    }
    __syncthreads();
    const int n = tid >> 3, i = tid & 7;
#pragma unroll
    for (int it = 0; it < 2; ++it) {
      int nn = n + it * 32;
      *(uint4*)(dst + (size_t)nn * K + i * 8) = *(const uint4*)&lt[nn * 72 + i * 8];
    }
  } else {
    const int bb = b - a.tblocks;
    int s = 0;
    while (s < PSEG - 1 && bb >= a.pstart[s + 1]) ++s;
    const int lb  = bb - a.pstart[s];
    const int nch = a.pchunks[s];
    const int kc  = a.kdiv8[s];
    const int N   = a.N[s];
#pragma unroll
    for (int j = 0; j < 4; ++j) {
      const int li = (lb * 4 + j) * 256 + tid;
      if (li >= nch) break;
      if (N == 1) {
        const float4* src = (const float4*)a.psrc[s] + (size_t)li * 2;
        float4 v0 = src[0], v1 = src[1];
        *(uint4*)(a.pdst[s] + (size_t)li * 8) = __builtin_bit_cast(uint4, cvt8(v0, v1));
      } else {
        int rn = li / kc;
        int k0 = (li - rn * kc) * 8;
        int cc = rn / N;
        int n  = rn - cc * N;
        const float* src = a.psrc[s] + ((size_t)cc * kc * 8 + k0) * N + n;
        bf16x8 r;
#pragma unroll
        for (int jj = 0; jj < 8; ++jj) r[jj] = (__bf16)src[(size_t)jj * N];
        *(uint4*)(a.pdst[s] + (size_t)rn * kc * 8 + k0) = __builtin_bit_cast(uint4, r);
      }
    }
  }
}

// ============================== launch =======================================
extern "C" void kernel_launch(void* const* d_in, const int* in_sizes, int n_in,
                              void* d_out, int out_size, void* d_ws, size_t ws_size,
                              hipStream_t stream) {
  const float* xf   = (const float*)d_in[0];
  const float* pW1f = (const float*)d_in[1];
  const float* pb1f = (const float*)d_in[2];
  const float* pW2f = (const float*)d_in[3];
  const float* pb2f = (const float*)d_in[4];
  const float* pW3f = (const float*)d_in[5];
  const float* pb3f = (const float*)d_in[6];
  const float* nW1f = (const float*)d_in[7];
  const float* nb1f = (const float*)d_in[8];
  const float* nW2f = (const float*)d_in[9];
  const float* nb2f = (const float*)d_in[10];
  const float* nW3f = (const float*)d_in[11];
  const float* nb3f = (const float*)d_in[12];
  const float* cW1f = (const float*)d_in[13];
  const float* cb1f = (const float*)d_in[14];
  const float* cW2f = (const float*)d_in[15];
  const float* cb2f = (const float*)d_in[16];
  const float* cW3f = (const float*)d_in[17];
  const float* cb3f = (const float*)d_in[18];

  float* out_emb = (float*)d_out;
  float* out_con = out_emb + (size_t)B_ * E_ * C_;

  const int cx   = B_ * IN_;          // 6291456
  const int cW1c = C_ * IN_ * H_;     // 3145728
  const int cW2c = C_ * H_ * H_;      // 262144
  const int cW3c = C_ * H_ * E_;      // 65536
  const int ccW1 = C_ * 2 * E_ * H_;  // 131072
  const int ccW3 = C_ * H_;           // 4096

  __bf16* w = (__bf16*)d_ws;
  size_t o = 0;
  __bf16* xw   = w + o; o += cx;
  __bf16* pw1t = w + o; o += cW1c;
  __bf16* nw1t = w + o; o += cW1c;
  __bf16* pw2t = w + o; o += cW2c;
  __bf16* nw2t = w + o; o += cW2c;
  __bf16* cw2t = w + o; o += cW2c;
  __bf16* pw3t = w + o; o += cW3c;
  __bf16* nw3t = w + o; o += cW3c;
  __bf16* cw1t = w + o; o += ccW1;
  __bf16* cw3w = w + o; o += ccW3;

  PrepArgs a;
  int tb = 0, pb = 0;
  {
    const float* tsrc[TSEG] = {pW1f, nW1f, pW2f, nW2f, cW2f};
    __bf16*      tdst[TSEG] = {pw1t, nw1t, pw2t, nw2t, cw2t};
    const int    tk[TSEG]   = {12,   12,   1,    1,    1};
    for (int i = 0; i < TSEG; ++i) {
      a.tsrc[i] = tsrc[i]; a.tdst[i] = tdst[i]; a.ktiles[i] = tk[i];
      a.tstart[i] = tb;
      tb += tk[i] * C_;
    }
    a.tstart[TSEG] = tb;
    a.tblocks = tb;

    const float* psrc[PSEG] = {xf, cW3f, pW3f, nW3f, cW1f};
    __bf16*      pdst[PSEG] = {xw, cw3w, pw3t, nw3t, cw1t};
    const int    pKs[PSEG]  = {0,  0,    64,   64,   32};
    const int    pNs[PSEG]  = {1,  1,    16,   16,   64};
    const int    pels[PSEG] = {cx, ccW3, cW3c, cW3c, ccW1};
    for (int i = 0; i < PSEG; ++i) {
      a.psrc[i] = psrc[i]; a.pdst[i] = pdst[i];
      a.pchunks[i] = pels[i] / 8;
      a.kdiv8[i] = (pNs[i] == 1) ? (pels[i] / 8) : (pKs[i] / 8);
      a.N[i] = pNs[i];
      a.pstart[i] = pb;
      pb += (pels[i] / 8 + 1023) / 1024;   // 256 threads x 4 chunks per block
    }
    a.pstart[PSEG] = pb;
  }
  prep_all<<<tb + pb, 256, 0, stream>>>(a);

  dim3 grid(B_ / BM_, C_);
  cb_fused_t<<<grid, 256, 0, stream>>>(xw,
      pw1t, pb1f, pw2t, pb2f, pw3t, pb3f,
      nw1t, nb1f, nw2t, nb2f, nw3t, nb3f,
      cw1t, cb1f, cw2t, cb2f, cw3w, cb3f,
      out_emb, out_con);
}

// Round 3
// 314.154 us; speedup vs baseline: 1.0647x; 1.0647x over previous
//
#include <hip/hip_runtime.h>
#include <hip/hip_bf16.h>

// ConceptBottleneck fused kernel, MI355X (gfx950).
// B=8192, IN=768, C=64, H=64, E=16.  Inputs/outputs fp32; internal math bf16 MFMA.
// cb_fused_t: grid (B/128, C); block = 128-row batch tile x one concept.
//   R3 (this): BARRIER-FREE TAIL + gll-prefetched tail weights.
//   - L1: async double-buffered [256][64] tiles via global_load_lds + counted
//     vmcnt(8) (never 0 in loop), XOR-swizzled source / swizzled reads (R2,
//     verified). 2 blocks/CU.
//   - After the loop, ALL tail weights (W2p|W2n|W3p|W3n|cW1|cW2 -> bufA, cw3 ->
//     cw3s) are issued as 33 global_load_lds (source pre-swizzled, linear LDS
//     dest); latency hides under the peeled tile-11 MFMA step + h1 epilogues;
//     one __syncthreads() drains them.
//   - TAIL IS WAVE-LOCAL: every A-fragment read row (wave*32+mt*16+l16) and
//     every epilogue write row (wave*32+mt*16+quad*4+r) lie in
//     [wave*32, wave*32+32). After the single weight-sync, L2(pos+neg) -> L3
//     (pos+neg) -> cp1 -> cp2 -> cp3 run with ZERO barriers (same-wave
//     in-order LDS dependencies only); one final __syncthreads() before the
//     cross-wave gate/output phase.
//   SPILL LAW (prev session): register state held across __syncthreads beyond
//   accumulators gets spilled -> all prefetch state lives in the vmcnt counter.

#define B_   8192
#define IN_  768
#define C_   64
#define H_   64
#define E_   16
#define BM_  128

typedef __bf16 bf16x8 __attribute__((ext_vector_type(8)));
typedef float  f32x4  __attribute__((ext_vector_type(4)));

__device__ __forceinline__ f32x4 mfma16(bf16x8 a, bf16x8 b, f32x4 c) {
  return __builtin_amdgcn_mfma_f32_16x16x32_bf16(a, b, c, 0, 0, 0);
}

__device__ __forceinline__ bf16x8 cvt8(float4 a, float4 b) {
  bf16x8 r;
  r[0] = (__bf16)a.x; r[1] = (__bf16)a.y; r[2] = (__bf16)a.z; r[3] = (__bf16)a.w;
  r[4] = (__bf16)b.x; r[5] = (__bf16)b.y; r[6] = (__bf16)b.z; r[7] = (__bf16)b.w;
  return r;
}

__device__ __forceinline__ void zero_acc(f32x4 (&acc)[2][4]) {
  const f32x4 z = {0.f, 0.f, 0.f, 0.f};
#pragma unroll
  for (int mt = 0; mt < 2; ++mt)
#pragma unroll
    for (int nt = 0; nt < 4; ++nt) acc[mt][nt] = z;
}

// 16B global -> LDS direct (vmcnt-counted; LDS dest = wave-uniform base + lane*16)
__device__ __forceinline__ void gll16(const __bf16* g, __bf16* l) {
  __builtin_amdgcn_global_load_lds(
      (const __attribute__((address_space(1))) unsigned int*)g,
      (__attribute__((address_space(3))) unsigned int*)l, 16, 0, 0);
}

// One gll16 covering 8 rows x 64 cols (1 KiB) of a row-major [R][64] matrix,
// source pre-swizzled so LDS slot (row, ch) holds global chunk ch^(row&7).
// rbase must be a multiple of 8.
__device__ __forceinline__ void gll_w64(const __bf16* M, __bf16* dst, int rbase, int lane) {
  const int lr = lane >> 3, lc = (lane & 7) ^ lr;
  gll16(M + (size_t)(rbase + lr) * 64 + lc * 8, dst + rbase * 64);
}

// One gll16 covering 16 rows x 32 cols of a [R][32] matrix; slot (row,ch) holds
// global chunk ch^(row&3). rbase multiple of 4 (we use multiples of 16).
__device__ __forceinline__ void gll_w32(const __bf16* M, __bf16* dst, int rbase, int lane) {
  const int lr = lane >> 2, lc = (lane & 3) ^ (lr & 3);
  gll16(M + (size_t)(rbase + lr) * 32 + lc * 8, dst + rbase * 32);
}

#define FENCE asm volatile("" ::: "memory")

// ============================ MAIN KERNEL ===================================
// LDS (76416 B -> 2 blocks/CU):
//  bufA[256*64] : L1 tile buffer 0 | tail: weight block
//                 W2p@0 W2n@4096 W3p@8192 W3n@9216 cW1@10240 cW2@12288 (els)
//  bufB[256*64] : L1 tile buffer 1 | tail: hbP [128][64]swz @0, hbN @8192
//  xcb[128][40] : pos|neg embeddings (cols 0..15 pos, 16..31 neg)
struct __align__(16) SmemT {
  __bf16 bufA[256 * 64];
  __bf16 bufB[256 * 64];
  __bf16 xcb[BM_ * 40];
  float  conc[BM_];
  __bf16 cw3s[64];
};
static_assert(sizeof(SmemT) == 76416, "layout");
static_assert(sizeof(SmemT) <= 81920, "LDS: need 2 blocks/CU");

// Epilogue to stride-64 XOR-swizzled buffer: col=nt*16+l16, row=w*32+mt*16+quad*4+r.
// Slot for global chunk g at row = g^(row&7).
__device__ __forceinline__ void epi64s(__bf16* hb, f32x4 (&acc)[2][4],
                                       const float* __restrict__ bias,
                                       int wave, int quad, int l16) {
#pragma unroll
  for (int nt = 0; nt < 4; ++nt) {
    const int ch = nt * 2 + (l16 >> 3);
    const int cl = l16 & 7;
    const float bv = bias[nt * 16 + l16];
#pragma unroll
    for (int mt = 0; mt < 2; ++mt)
#pragma unroll
      for (int r = 0; r < 4; ++r) {
        const int row = wave * 32 + mt * 16 + quad * 4 + r;
        hb[row * 64 + (((ch ^ (row & 7)) << 3) | cl)] =
            (__bf16)fmaxf(acc[mt][nt][r] + bv, 0.f);
      }
  }
}

// [128,64] @ [64,64]: A, B both stride-64 XOR-swizzled (slot = chunk^(row&7)).
__device__ __forceinline__ void gemm64s(const __bf16* A, const __bf16* Bm,
                                        f32x4 (&acc)[2][4], int wave, int quad, int l16) {
  const int s7 = l16 & 7;
#pragma unroll
  for (int ks = 0; ks < 2; ++ks) {
    const int off = ((ks * 4 + quad) ^ s7) * 8;
    bf16x8 a[2], bb[4];
#pragma unroll
    for (int mt = 0; mt < 2; ++mt)
      a[mt] = *(const bf16x8*)(A + (wave * 32 + mt * 16 + l16) * 64 + off);
#pragma unroll
    for (int nt = 0; nt < 4; ++nt)
      bb[nt] = *(const bf16x8*)(Bm + (nt * 16 + l16) * 64 + off);
#pragma unroll
    for (int mt = 0; mt < 2; ++mt)
#pragma unroll
      for (int nt = 0; nt < 4; ++nt)
        acc[mt][nt] = mfma16(a[mt], bb[nt], acc[mt][nt]);
  }
}

// Layer-3: e = h2 @ W3t -> xcb[:, xc_off..+16). A swizzled, B16 = [16][64] swizzled.
__device__ __forceinline__ void l3s(const __bf16* A, const __bf16* B16,
                                    __bf16* xcb, const float* __restrict__ b3,
                                    int xc_off, int wave, int quad, int l16) {
  const int s7 = l16 & 7;
  f32x4 acc3[2];
  { const f32x4 z = {0.f, 0.f, 0.f, 0.f}; acc3[0] = z; acc3[1] = z; }
#pragma unroll
  for (int ks = 0; ks < 2; ++ks) {
    const int off = ((ks * 4 + quad) ^ s7) * 8;
    bf16x8 bb = *(const bf16x8*)(B16 + l16 * 64 + off);
#pragma unroll
    for (int mt = 0; mt < 2; ++mt) {
      bf16x8 a = *(const bf16x8*)(A + (wave * 32 + mt * 16 + l16) * 64 + off);
      acc3[mt] = mfma16(a, bb, acc3[mt]);
    }
  }
  const float bv = b3[l16];
#pragma unroll
  for (int mt = 0; mt < 2; ++mt)
#pragma unroll
    for (int r = 0; r < 4; ++r) {
      const int row = wave * 32 + mt * 16 + quad * 4 + r;
      xcb[row * 40 + xc_off + l16] = (__bf16)(acc3[mt][r] + bv);
    }
}

// L1 MFMA step on a [256][64] swizzled buffer: rows 0-127 x, 128-191 posW, 192-255 negW.
__device__ __forceinline__ void l1_step(const __bf16* cbuf,
                                        f32x4 (&accP)[2][4], f32x4 (&accN)[2][4],
                                        int wave, int quad, int l16) {
  const int sx = l16 & 7;
#pragma unroll
  for (int ks = 0; ks < 2; ++ks) {
    const int pc = ((ks * 4 + quad) ^ sx) * 8;
    bf16x8 a[2], bp[4], bn[4];
#pragma unroll
    for (int mt = 0; mt < 2; ++mt)
      a[mt] = *(const bf16x8*)(cbuf + (wave * 32 + mt * 16 + l16) * 64 + pc);
#pragma unroll
    for (int nt = 0; nt < 4; ++nt) {
      bp[nt] = *(const bf16x8*)(cbuf + (128 + nt * 16 + l16) * 64 + pc);
      bn[nt] = *(const bf16x8*)(cbuf + (192 + nt * 16 + l16) * 64 + pc);
    }
#pragma unroll
    for (int mt = 0; mt < 2; ++mt)
#pragma unroll
      for (int nt = 0; nt < 4; ++nt) {
        accP[mt][nt] = mfma16(a[mt], bp[nt], accP[mt][nt]);
        accN[mt][nt] = mfma16(a[mt], bn[nt], accN[mt][nt]);
      }
  }
}

__global__ __launch_bounds__(256, 2) void cb_fused_t(
    const __bf16* __restrict__ x,
    const __bf16* __restrict__ pW1t, const float* __restrict__ pb1,
    const __bf16* __restrict__ pW2t, const float* __restrict__ pb2,
    const __bf16* __restrict__ pW3t, const float* __restrict__ pb3,
    const __bf16* __restrict__ nW1t, const float* __restrict__ nb1,
    const __bf16* __restrict__ nW2t, const float* __restrict__ nb2,
    const __bf16* __restrict__ nW3t, const float* __restrict__ nb3,
    const __bf16* __restrict__ cW1t, const float* __restrict__ cb1,
    const __bf16* __restrict__ cW2t, const float* __restrict__ cb2,
    const __bf16* __restrict__ cw3,  const float* __restrict__ cb3,
    float* __restrict__ out_emb, float* __restrict__ out_con)
{
  __shared__ SmemT sm;
  const int tid  = threadIdx.x;
  const int wave = tid >> 6, lane = tid & 63;
  const int quad = lane >> 4, l16 = lane & 15;
  const int row0 = blockIdx.x * BM_;
  const int c    = blockIdx.y;

  // per-concept pointers
  const __bf16* pg   = pW1t + (size_t)c * 64 * IN_;
  const __bf16* ng   = nW1t + (size_t)c * 64 * IN_;
  const float*  pb1c = pb1 + c * 64;
  const float*  nb1c = nb1 + c * 64;
  const float*  pb2c = pb2 + c * 64;
  const float*  nb2c = nb2 + c * 64;

  // ---------- layer 1 COMBINED, async double-buffered (R2, verified) ----------
  f32x4 accP[2][4]; zero_acc(accP);
  f32x4 accN[2][4]; zero_acc(accN);

  const __bf16* xg = x + (size_t)row0 * IN_;
  const int lrow   = lane >> 3;             // 0..7 within segment
  const int lchunk = (lane & 7) ^ lrow;     // swizzled source chunk
  const __bf16* gsrc = (wave == 0) ? xg
                     : (wave == 1) ? xg + 64 * IN_
                     : (wave == 2) ? pg : ng;
  const __bf16* gl = gsrc + (size_t)lrow * IN_ + lchunk * 8;  // per-lane base
  __bf16* const dA = sm.bufA + wave * 64 * 64;   // wave-uniform LDS bases
  __bf16* const dB = sm.bufB + wave * 64 * 64;

  // prologue: tile 0 -> bufA
#pragma unroll
  for (int j = 0; j < 8; ++j)
    gll16(gl + j * 8 * IN_, dA + j * 8 * 64);

  for (int kt = 0; kt < 11; ++kt) {
    // issue tile kt+1 into the other buffer (stays in flight across barriers)
    {
      const __bf16* gk = gl + (kt + 1) * 64;
      __bf16* nd = (kt & 1) ? dA : dB;
#pragma unroll
      for (int j = 0; j < 8; ++j)
        gll16(gk + j * 8 * IN_, nd + j * 8 * 64);
    }
    // wait tile kt (8 older ops) landed; tile kt+1 (8 newest) still in flight
    asm volatile("s_waitcnt vmcnt(8)" ::: "memory");
    __builtin_amdgcn_s_barrier();
    __builtin_amdgcn_sched_barrier(0);
    FENCE;
    l1_step((kt & 1) ? sm.bufB : sm.bufA, accP, accN, wave, quad, l16);
    FENCE;
    __builtin_amdgcn_s_barrier();   // reads done before next iter overwrites
    __builtin_amdgcn_sched_barrier(0);
    FENCE;
  }

  // ---------- prefetch ALL tail weights into bufA (dead after kt=10) ----------
  // 33 gll16 total, split by wave: w0=W2p(8)+cw3(1), w1=W2n(8), w2=W3p+W3n+cW1(8),
  // w3=cW2(8). Latency hides under peeled tile-11 step + h1 epilogues.
  {
    __bf16* WT = sm.bufA;
    if (wave == 0) {
      const __bf16* M = pW2t + (size_t)c * 4096;
#pragma unroll
      for (int g = 0; g < 8; ++g) gll_w64(M, WT, g * 8, lane);
      if (lane < 8) gll16(cw3 + (size_t)c * 64 + lane * 8, sm.cw3s);
    } else if (wave == 1) {
      const __bf16* M = nW2t + (size_t)c * 4096;
#pragma unroll
      for (int g = 0; g < 8; ++g) gll_w64(M, WT + 4096, g * 8, lane);
    } else if (wave == 2) {
      const __bf16* m3p = pW3t + (size_t)c * 1024;
      const __bf16* m3n = nW3t + (size_t)c * 1024;
      const __bf16* mc1 = cW1t + (size_t)c * 2048;
      gll_w64(m3p, WT + 8192, 0, lane);
      gll_w64(m3p, WT + 8192, 8, lane);
      gll_w64(m3n, WT + 9216, 0, lane);
      gll_w64(m3n, WT + 9216, 8, lane);
      gll_w32(mc1, WT + 10240, 0,  lane);
      gll_w32(mc1, WT + 10240, 16, lane);
      gll_w32(mc1, WT + 10240, 32, lane);
      gll_w32(mc1, WT + 10240, 48, lane);
    } else {
      const __bf16* M = cW2t + (size_t)c * 4096;
#pragma unroll
      for (int g = 0; g < 8; ++g) gll_w64(M, WT + 12288, g * 8, lane);
    }
  }

  // peeled tile 11 (in bufB): wait its 8 loads (tail glls are the <=9 newest)
  asm volatile("s_waitcnt vmcnt(8)" ::: "memory");
  __builtin_amdgcn_s_barrier();
  __builtin_amdgcn_sched_barrier(0);
  FENCE;
  l1_step(sm.bufB, accP, accN, wave, quad, l16);
  FENCE;
  __builtin_amdgcn_s_barrier();   // all tile-11 reads done before hbN overwrites W rows
  __builtin_amdgcn_sched_barrier(0);
  FENCE;

  __bf16* WT  = sm.bufA;
  __bf16* hbP = sm.bufB;
  __bf16* hbN = sm.bufB + 8192;

  // h1 epilogues (wave-local rows; cross-wave hazard covered by barrier above)
  epi64s(hbP, accP, pb1c, wave, quad, l16);
  epi64s(hbN, accN, nb1c, wave, quad, l16);
  __syncthreads();   // drains this wave's tail glls (vmcnt 0) + barrier -> weights visible

  // ================= BARRIER-FREE WAVE-LOCAL TAIL =================
  // L2 pos+neg
  f32x4 acc2P[2][4]; zero_acc(acc2P);
  f32x4 acc2N[2][4]; zero_acc(acc2N);
  gemm64s(hbP, WT,        acc2P, wave, quad, l16);
  gemm64s(hbN, WT + 4096, acc2N, wave, quad, l16);
  epi64s(hbP, acc2P, pb2c, wave, quad, l16);
  epi64s(hbN, acc2N, nb2c, wave, quad, l16);

  // L3 pos+neg -> xcb
  l3s(hbP, WT + 8192, sm.xcb, pb3 + c * 16, 0,  wave, quad, l16);
  l3s(hbN, WT + 9216, sm.xcb, nb3 + c * 16, 16, wave, quad, l16);

  // cp layer 1: [128,32] @ [32,64]; A = xcb (stride 40), B = cW1 [64][32] swz(row&3)
  f32x4 acc1[2][4]; zero_acc(acc1);
  {
    bf16x8 a[2], bb[4];
#pragma unroll
    for (int mt = 0; mt < 2; ++mt)
      a[mt] = *(const bf16x8*)&sm.xcb[(wave * 32 + mt * 16 + l16) * 40 + quad * 8];
#pragma unroll
    for (int nt = 0; nt < 4; ++nt)
      bb[nt] = *(const bf16x8*)(WT + 10240 + (nt * 16 + l16) * 32 +
                                ((quad ^ (l16 & 3)) * 8));
#pragma unroll
    for (int mt = 0; mt < 2; ++mt)
#pragma unroll
      for (int nt = 0; nt < 4; ++nt)
        acc1[mt][nt] = mfma16(a[mt], bb[nt], acc1[mt][nt]);
  }
  epi64s(hbP, acc1, cb1 + c * 64, wave, quad, l16);

  // cp layer 2
  f32x4 accC[2][4]; zero_acc(accC);
  gemm64s(hbP, WT + 12288, accC, wave, quad, l16);
  epi64s(hbP, accC, cb2 + c * 64, wave, quad, l16);

  // cp layer 3 (N=1 via MFMA; B nonzero only in lane col 0)
  {
    f32x4 acc3[2];
    { const f32x4 z = {0.f, 0.f, 0.f, 0.f}; acc3[0] = z; acc3[1] = z; }
    const int s7 = l16 & 7;
#pragma unroll
    for (int ks = 0; ks < 2; ++ks) {
      const int off = ((ks * 4 + quad) ^ s7) * 8;
      bf16x8 bb = {};
      if (l16 == 0) bb = *(const bf16x8*)&sm.cw3s[ks * 32 + quad * 8];
#pragma unroll
      for (int mt = 0; mt < 2; ++mt) {
        bf16x8 a = *(const bf16x8*)(hbP + (wave * 32 + mt * 16 + l16) * 64 + off);
        acc3[mt] = mfma16(a, bb, acc3[mt]);
      }
    }
    if (l16 == 0) {
      float bv = cb3[c];
#pragma unroll
      for (int mt = 0; mt < 2; ++mt)
#pragma unroll
        for (int r = 0; r < 4; ++r)
          sm.conc[wave * 32 + mt * 16 + quad * 4 + r] = acc3[mt][r] + bv;
    }
  }
  __syncthreads();   // conc + xcb now needed cross-wave

  // ---- gate + outputs (fp32) ----
  for (int ii = tid; ii < BM_ * E_; ii += 256) {
    int row = ii >> 4, e = ii & 15;
    float cv = sm.conc[row];
    float w  = fminf(fmaxf(cv * 0.5f + 0.5f, 0.f), 1.f);
    float pv2 = (float)sm.xcb[row * 40 + e];
    float nv2 = (float)sm.xcb[row * 40 + 16 + e];
    out_emb[(size_t)(row0 + row) * (E_ * C_) + e * C_ + c] = pv2 * w + nv2 * (1.f - w);
  }
  if (tid < 128) out_con[(size_t)(row0 + tid) * C_ + c] = sm.conc[tid];
}

// ------------- prep_all: ONE flat 1D launch, no dead blocks -------------------
#define TSEG 5
#define PSEG 5
struct PrepArgs {
  const float* tsrc[TSEG];
  __bf16*      tdst[TSEG];
  int tstart[TSEG + 1];
  int ktiles[TSEG];            // K/64
  const float* psrc[PSEG];
  __bf16*      pdst[PSEG];
  int pstart[PSEG + 1];        // block starts (after tblocks)
  int pchunks[PSEG];           // total 8-elem chunks in segment
  int kdiv8[PSEG];
  int N[PSEG];                 // 1 = plain copy, else transpose inner stride
  int tblocks;
};

__global__ __launch_bounds__(256) void prep_all(PrepArgs a) {
  const int tid = threadIdx.x;
  const int b = blockIdx.x;
  __shared__ __bf16 lt[64 * 72];
  if (b < a.tblocks) {
    int s = 0;
    while (s < TSEG - 1 && b >= a.tstart[s + 1]) ++s;
    const int idx = b - a.tstart[s];
    const int kt = idx % a.ktiles[s];
    const int c  = idx / a.ktiles[s];
    const int K  = a.ktiles[s] * 64;
    const float* src = a.tsrc[s] + (size_t)c * K * 64 + (size_t)kt * 64 * 64;
    __bf16*      dst = a.tdst[s] + (size_t)c * 64 * K + kt * 64;
    const int r = tid >> 4, c4 = (tid & 15) * 4;
#pragma unroll
    for (int it = 0; it < 4; ++it) {
      int k = r + it * 16;
      float4 v = *(const float4*)(src + (size_t)k * 64 + c4);
      lt[(c4 + 0) * 72 + k] = (__bf16)v.x;
      lt[(c4 + 1) * 72 + k] = (__bf16)v.y;
      lt[(c4 + 2) * 72 + k] = (__bf16)v.z;
      lt[(c4 + 3) * 72 + k] = (__bf16)v.w;
    }
    __syncthreads();
    const int n = tid >> 3, i = tid & 7;
#pragma unroll
    for (int it = 0; it < 2; ++it) {
      int nn = n + it * 32;
      *(uint4*)(dst + (size_t)nn * K + i * 8) = *(const uint4*)&lt[nn * 72 + i * 8];
    }
  } else {
    const int bb = b - a.tblocks;
    int s = 0;
    while (s < PSEG - 1 && bb >= a.pstart[s + 1]) ++s;
    const int lb  = bb - a.pstart[s];
    const int nch = a.pchunks[s];
    const int kc  = a.kdiv8[s];
    const int N   = a.N[s];
#pragma unroll
    for (int j = 0; j < 4; ++j) {
      const int li = (lb * 4 + j) * 256 + tid;
      if (li >= nch) break;
      if (N == 1) {
        const float4* src = (const float4*)a.psrc[s] + (size_t)li * 2;
        float4 v0 = src[0], v1 = src[1];
        *(uint4*)(a.pdst[s] + (size_t)li * 8) = __builtin_bit_cast(uint4, cvt8(v0, v1));
      } else {
        int rn = li / kc;
        int k0 = (li - rn * kc) * 8;
        int cc = rn / N;
        int n  = rn - cc * N;
        const float* src = a.psrc[s] + ((size_t)cc * kc * 8 + k0) * N + n;
        bf16x8 r;
#pragma unroll
        for (int jj = 0; jj < 8; ++jj) r[jj] = (__bf16)src[(size_t)jj * N];
        *(uint4*)(a.pdst[s] + (size_t)rn * kc * 8 + k0) = __builtin_bit_cast(uint4, r);
      }
    }
  }
}

// ============================== launch =======================================
extern "C" void kernel_launch(void* const* d_in, const int* in_sizes, int n_in,
                              void* d_out, int out_size, void* d_ws, size_t ws_size,
                              hipStream_t stream) {
  const float* xf   = (const float*)d_in[0];
  const float* pW1f = (const float*)d_in[1];
  const float* pb1f = (const float*)d_in[2];
  const float* pW2f = (const float*)d_in[3];
  const float* pb2f = (const float*)d_in[4];
  const float* pW3f = (const float*)d_in[5];
  const float* pb3f = (const float*)d_in[6];
  const float* nW1f = (const float*)d_in[7];
  const float* nb1f = (const float*)d_in[8];
  const float* nW2f = (const float*)d_in[9];
  const float* nb2f = (const float*)d_in[10];
  const float* nW3f = (const float*)d_in[11];
  const float* nb3f = (const float*)d_in[12];
  const float* cW1f = (const float*)d_in[13];
  const float* cb1f = (const float*)d_in[14];
  const float* cW2f = (const float*)d_in[15];
  const float* cb2f = (const float*)d_in[16];
  const float* cW3f = (const float*)d_in[17];
  const float* cb3f = (const float*)d_in[18];

  float* out_emb = (float*)d_out;
  float* out_con = out_emb + (size_t)B_ * E_ * C_;

  const int cx   = B_ * IN_;          // 6291456
  const int cW1c = C_ * IN_ * H_;     // 3145728
  const int cW2c = C_ * H_ * H_;      // 262144
  const int cW3c = C_ * H_ * E_;      // 65536
  const int ccW1 = C_ * 2 * E_ * H_;  // 131072
  const int ccW3 = C_ * H_;           // 4096

  __bf16* w = (__bf16*)d_ws;
  size_t o = 0;
  __bf16* xw   = w + o; o += cx;
  __bf16* pw1t = w + o; o += cW1c;
  __bf16* nw1t = w + o; o += cW1c;
  __bf16* pw2t = w + o; o += cW2c;
  __bf16* nw2t = w + o; o += cW2c;
  __bf16* cw2t = w + o; o += cW2c;
  __bf16* pw3t = w + o; o += cW3c;
  __bf16* nw3t = w + o; o += cW3c;
  __bf16* cw1t = w + o; o += ccW1;
  __bf16* cw3w = w + o; o += ccW3;

  PrepArgs a;
  int tb = 0, pb = 0;
  {
    const float* tsrc[TSEG] = {pW1f, nW1f, pW2f, nW2f, cW2f};
    __bf16*      tdst[TSEG] = {pw1t, nw1t, pw2t, nw2t, cw2t};
    const int    tk[TSEG]   = {12,   12,   1,    1,    1};
    for (int i = 0; i < TSEG; ++i) {
      a.tsrc[i] = tsrc[i]; a.tdst[i] = tdst[i]; a.ktiles[i] = tk[i];
      a.tstart[i] = tb;
      tb += tk[i] * C_;
    }
    a.tstart[TSEG] = tb;
    a.tblocks = tb;

    const float* psrc[PSEG] = {xf, cW3f, pW3f, nW3f, cW1f};
    __bf16*      pdst[PSEG] = {xw, cw3w, pw3t, nw3t, cw1t};
    const int    pKs[PSEG]  = {0,  0,    64,   64,   32};
    const int    pNs[PSEG]  = {1,  1,    16,   16,   64};
    const int    pels[PSEG] = {cx, ccW3, cW3c, cW3c, ccW1};
    for (int i = 0; i < PSEG; ++i) {
      a.psrc[i] = psrc[i]; a.pdst[i] = pdst[i];
      a.pchunks[i] = pels[i] / 8;
      a.kdiv8[i] = (pNs[i] == 1) ? (pels[i] / 8) : (pKs[i] / 8);
      a.N[i] = pNs[i];
      a.pstart[i] = pb;
      pb += (pels[i] / 8 + 1023) / 1024;   // 256 threads x 4 chunks per block
    }
    a.pstart[PSEG] = pb;
  }
  prep_all<<<tb + pb, 256, 0, stream>>>(a);

  dim3 grid(B_ / BM_, C_);
  cb_fused_t<<<grid, 256, 0, stream>>>(xw,
      pw1t, pb1f, pw2t, pb2f, pw3t, pb3f,
      nw1t, nb1f, nw2t, nb2f, nw3t, nb3f,
      cw1t, cb1f, cw2t, cb2f, cw3w, cb3f,
      out_emb, out_con);
}